// Round 6
// baseline (393.676 us; speedup 1.0000x reference)
//
#include <hip/hip_runtime.h>

#define F_IN 64
#define NH 4
#define HC 128
#define NEG_SLOPE 0.2f
#define LN_EPS 1e-5f

// ---------------------------------------------------------------------------
// K0: detect whether edge_index arrived as int64 (little-endian) or int32.
// ---------------------------------------------------------------------------
__global__ void k0_detect(const int* __restrict__ ei, int E, int* __restrict__ flag) {
    __shared__ int any_nz;
    if (threadIdx.x == 0) any_nz = 0;
    __syncthreads();
    long long stride = (2LL * E) / 257;
    long long pos = (long long)(threadIdx.x + 1) * stride;
    int w = ei[pos | 1];
    if (w != 0) atomicOr(&any_nz, 1);
    __syncthreads();
    if (threadIdx.x == 0) flag[0] = (any_nz == 0) ? 1 : 0;   // 1 => int64
}

__device__ inline unsigned bfpack(float a, float b) {
    unsigned ua = __float_as_uint(a), ub = __float_as_uint(b);
    ua = (ua + 0x7fffu + ((ua >> 16) & 1u)) >> 16;           // RNE to bf16
    ub = (ub + 0x7fffu + ((ub >> 16) & 1u)) >> 16;
    return ua | (ub << 16);
}

// ---------------------------------------------------------------------------
// KA: fused dual GEMM: h_bf16 = x@W (rounded), r = x@res_w, PLUS attention
// logits a_s/a_d from the f32 accumulators (8-lane shfl reduce).
// ---------------------------------------------------------------------------
#define NT 64
#define XS_LD 66
__global__ __launch_bounds__(256) void kA_gemm(
    const float* __restrict__ x, const float* __restrict__ W,
    const float* __restrict__ res_w,
    const float* __restrict__ att_src, const float* __restrict__ att_dst,
    unsigned int* __restrict__ h_bf, float* __restrict__ r,
    float* __restrict__ a_s, float* __restrict__ a_d, int n)
{
    __shared__ float Ws[F_IN * HC];
    __shared__ float xs[NT * XS_LD];
    int tid = threadIdx.x;
    int j = tid & 15, i = tid >> 4;
    int nb0 = blockIdx.x * NT;

#pragma unroll
    for (int it = 0; it < 8; ++it) {
        int f2 = it * 256 + tid;
        int node = f2 >> 5, k2 = f2 & 31;
        int src = nb0 + node; if (src >= n) src = n - 1;
        float2 v = *(const float2*)&x[src * F_IN + k2 * 2];
        xs[node * XS_LD + k2 * 2]     = v.x;
        xs[node * XS_LD + k2 * 2 + 1] = v.y;
    }

    for (int half = 0; half < 2; ++half) {
        __syncthreads();
        {
            const float4* src4 = (const float4*)(half ? res_w : W);
            float4* Ws4 = (float4*)Ws;
            for (int it = tid; it < F_IN * HC / 4; it += 256) Ws4[it] = src4[it];
        }
        __syncthreads();

        for (int cg = 0; cg < 2; ++cg) {
            float acc[4][4];
#pragma unroll
            for (int m = 0; m < 4; ++m)
#pragma unroll
                for (int c = 0; c < 4; ++c) acc[m][c] = 0.f;

            const float* wbase = &Ws[cg * 64 + j * 4];
            const float* xbase = &xs[(i * 4) * XS_LD];
#pragma unroll 8
            for (int k2 = 0; k2 < 32; ++k2) {
                float2 xv0 = *(const float2*)&xbase[0 * XS_LD + 2 * k2];
                float2 xv1 = *(const float2*)&xbase[1 * XS_LD + 2 * k2];
                float2 xv2 = *(const float2*)&xbase[2 * XS_LD + 2 * k2];
                float2 xv3 = *(const float2*)&xbase[3 * XS_LD + 2 * k2];
                float4 w0 = *(const float4*)&wbase[(2 * k2) * HC];
                float4 w1 = *(const float4*)&wbase[(2 * k2 + 1) * HC];
                acc[0][0] += xv0.x * w0.x + xv0.y * w1.x;
                acc[0][1] += xv0.x * w0.y + xv0.y * w1.y;
                acc[0][2] += xv0.x * w0.z + xv0.y * w1.z;
                acc[0][3] += xv0.x * w0.w + xv0.y * w1.w;
                acc[1][0] += xv1.x * w0.x + xv1.y * w1.x;
                acc[1][1] += xv1.x * w0.y + xv1.y * w1.y;
                acc[1][2] += xv1.x * w0.z + xv1.y * w1.z;
                acc[1][3] += xv1.x * w0.w + xv1.y * w1.w;
                acc[2][0] += xv2.x * w0.x + xv2.y * w1.x;
                acc[2][1] += xv2.x * w0.y + xv2.y * w1.y;
                acc[2][2] += xv2.x * w0.z + xv2.y * w1.z;
                acc[2][3] += xv2.x * w0.w + xv2.y * w1.w;
                acc[3][0] += xv3.x * w0.x + xv3.y * w1.x;
                acc[3][1] += xv3.x * w0.y + xv3.y * w1.y;
                acc[3][2] += xv3.x * w0.z + xv3.y * w1.z;
                acc[3][3] += xv3.x * w0.w + xv3.y * w1.w;
            }

            if (half == 0) {
                float4 asv = *(const float4*)&att_src[cg * 64 + j * 4];
                float4 adv = *(const float4*)&att_dst[cg * 64 + j * 4];
                int head = cg * 2 + (j >> 3);
#pragma unroll
                for (int m = 0; m < 4; ++m) {
                    int node = nb0 + i * 4 + m;
                    float vs = acc[m][0] * asv.x + acc[m][1] * asv.y
                             + acc[m][2] * asv.z + acc[m][3] * asv.w;
                    float vd = acc[m][0] * adv.x + acc[m][1] * adv.y
                             + acc[m][2] * adv.z + acc[m][3] * adv.w;
                    vs += __shfl_down(vs, 4, 8); vd += __shfl_down(vd, 4, 8);
                    vs += __shfl_down(vs, 2, 8); vd += __shfl_down(vd, 2, 8);
                    vs += __shfl_down(vs, 1, 8); vd += __shfl_down(vd, 1, 8);
                    if (node < n) {
                        if ((j & 7) == 0) {
                            a_s[node * NH + head] = vs;
                            a_d[node * NH + head] = vd;
                        }
                        uint2 p = make_uint2(bfpack(acc[m][0], acc[m][1]),
                                             bfpack(acc[m][2], acc[m][3]));
                        *(uint2*)&h_bf[node * 64 + cg * 32 + j * 2] = p;
                    }
                }
            } else {
#pragma unroll
                for (int m = 0; m < 4; ++m) {
                    int node = nb0 + i * 4 + m;
                    if (node < n)
                        *(float4*)&r[node * HC + cg * 64 + j * 4] =
                            make_float4(acc[m][0], acc[m][1], acc[m][2], acc[m][3]);
                }
            }
        }
    }
}

// ---------------------------------------------------------------------------
// Counting sort: hist -> 3-phase multi-block scan -> range-owned scatter
// ---------------------------------------------------------------------------
__global__ __launch_bounds__(256) void k_hist(const int* __restrict__ ei, int E,
                                              const int* __restrict__ flag, int* __restrict__ deg)
{
    int idx = blockIdx.x * 256 + threadIdx.x;
    if (idx >= E) return;
    int d = flag[0] ? ei[2 * (E + idx)] : ei[E + idx];
    atomicAdd(&deg[d], 1);
}

__global__ __launch_bounds__(256) void k_scan_p1(const int* __restrict__ deg, int n,
                                                 int* __restrict__ bsums)
{
    __shared__ int red[4];
    int i = blockIdx.x * 256 + threadIdx.x;
    int v = (i < n) ? deg[i] : 0;
#pragma unroll
    for (int off = 32; off > 0; off >>= 1) v += __shfl_down(v, off, 64);
    int lane = threadIdx.x & 63, wv = threadIdx.x >> 6;
    if (lane == 0) red[wv] = v;
    __syncthreads();
    if (threadIdx.x == 0)
        bsums[blockIdx.x] = red[0] + red[1] + red[2] + red[3];
}

__global__ __launch_bounds__(256) void k_scan_p2(int* __restrict__ bsums, int nblk)
{
    __shared__ int sh[256];
    int t = threadIdx.x;
    int v = (t < nblk) ? bsums[t] : 0;
    sh[t] = v;
    __syncthreads();
#pragma unroll
    for (int off = 1; off < 256; off <<= 1) {
        int u = (t >= off) ? sh[t - off] : 0;
        __syncthreads();
        sh[t] += u;
        __syncthreads();
    }
    if (t < nblk) bsums[t] = sh[t] - v;
}

__global__ __launch_bounds__(256) void k_scan_p3(int* __restrict__ deg_off,
                                                 const int* __restrict__ bsums,
                                                 int n, int E)
{
    __shared__ int sh[256];
    int t = threadIdx.x;
    int i = blockIdx.x * 256 + t;
    int v = (i < n) ? deg_off[i] : 0;
    sh[t] = v;
    __syncthreads();
#pragma unroll
    for (int off = 1; off < 256; off <<= 1) {
        int u = (t >= off) ? sh[t - off] : 0;
        __syncthreads();
        sh[t] += u;
        __syncthreads();
    }
    int excl = sh[t] - v + bsums[blockIdx.x];
    if (i < n) deg_off[i] = excl;
    if (blockIdx.x == 0 && t == 0) deg_off[n] = E;
}

// ---------------------------------------------------------------------------
// K_scatter2: block b owns dst range [b*512, b*512+512). Streams the whole
// dst array (coalesced int4), keeps owned edges, LDS cursors, and writes a
// PRIVATE contiguous CSR slice -> no cross-XCD line sharing, no global atomics.
// ---------------------------------------------------------------------------
#define SC_RANGE 512
__global__ __launch_bounds__(1024) void k_scatter2(
    const int* __restrict__ ei, int E, int n, const int* __restrict__ flag,
    const int* __restrict__ offsets, int* __restrict__ src_sorted)
{
    __shared__ int cur[SC_RANGE];
    int r0 = blockIdx.x * SC_RANGE;
    int r1 = min(n, r0 + SC_RANGE);
    for (int t = threadIdx.x; t < r1 - r0; t += 1024) cur[t] = offsets[r0 + t];
    __syncthreads();
    int is64 = flag[0];

    if (!is64) {
        const int* dst = ei + E;
        if ((((size_t)dst) & 15) == 0) {
            const int4* dst4 = (const int4*)dst;
            int nq = E >> 2;
            for (int q = threadIdx.x; q < nq; q += 1024) {
                int4 dv = dst4[q];
                int base = q * 4;
                if (dv.x >= r0 && dv.x < r1) { int p = atomicAdd(&cur[dv.x - r0], 1); src_sorted[p] = ei[base]; }
                if (dv.y >= r0 && dv.y < r1) { int p = atomicAdd(&cur[dv.y - r0], 1); src_sorted[p] = ei[base + 1]; }
                if (dv.z >= r0 && dv.z < r1) { int p = atomicAdd(&cur[dv.z - r0], 1); src_sorted[p] = ei[base + 2]; }
                if (dv.w >= r0 && dv.w < r1) { int p = atomicAdd(&cur[dv.w - r0], 1); src_sorted[p] = ei[base + 3]; }
            }
            for (int idx = (nq << 2) + threadIdx.x; idx < E; idx += 1024) {
                int d = dst[idx];
                if (d >= r0 && d < r1) { int p = atomicAdd(&cur[d - r0], 1); src_sorted[p] = ei[idx]; }
            }
        } else {
            for (int idx = threadIdx.x; idx < E; idx += 1024) {
                int d = dst[idx];
                if (d >= r0 && d < r1) { int p = atomicAdd(&cur[d - r0], 1); src_sorted[p] = ei[idx]; }
            }
        }
    } else {
        const int* dst = ei + 2 * E;     // int64 dst array (low words at even dwords)
        if ((((size_t)dst) & 15) == 0) {
            const int4* dst4 = (const int4*)dst;
            int nq = E >> 1;             // one int4 = 2 int64 values
            for (int q = threadIdx.x; q < nq; q += 1024) {
                int4 dv = dst4[q];
                int base = q * 2;
                if (dv.x >= r0 && dv.x < r1) { int p = atomicAdd(&cur[dv.x - r0], 1); src_sorted[p] = ei[2 * base]; }
                if (dv.z >= r0 && dv.z < r1) { int p = atomicAdd(&cur[dv.z - r0], 1); src_sorted[p] = ei[2 * (base + 1)]; }
            }
            for (int idx = (nq << 1) + threadIdx.x; idx < E; idx += 1024) {
                int d = dst[2 * idx];
                if (d >= r0 && d < r1) { int p = atomicAdd(&cur[d - r0], 1); src_sorted[p] = ei[2 * idx]; }
            }
        } else {
            for (int idx = threadIdx.x; idx < E; idx += 1024) {
                int d = dst[2 * idx];
                if (d >= r0 && d < r1) { int p = atomicAdd(&cur[d - r0], 1); src_sorted[p] = ei[2 * idx]; }
            }
        }
    }
}

// ---------------------------------------------------------------------------
// K_agg: wave-per-dst CSR gather + softmax + full fused epilogue.
// ---------------------------------------------------------------------------
__device__ inline float wave_bcast_sum(float v) {
#pragma unroll
    for (int off = 32; off > 0; off >>= 1) v += __shfl_down(v, off, 64);
    return __shfl(v, 0, 64);
}

__global__ __launch_bounds__(256) void k_agg(
    const int* __restrict__ offsets, const int* __restrict__ src_sorted,
    const float* __restrict__ a_s, const float* __restrict__ a_d,
    const unsigned int* __restrict__ h_bf, const float* __restrict__ r,
    const float* __restrict__ bias, const float* __restrict__ res_b,
    const float* __restrict__ ln_g, const float* __restrict__ ln_b,
    float* __restrict__ out, int n)
{
    int wv = threadIdx.x >> 6, lane = threadIdx.x & 63;
    int d = blockIdx.x * 4 + wv;
    if (d >= n) return;
    int c0 = lane * 2, head = lane >> 4;
    float ad = a_d[d * NH + head];

    float e = a_s[d * NH + head] + ad;
    e = (e >= 0.f) ? e : NEG_SLOPE * e;
    float w = __expf(e);
    float denom = w;
    unsigned hv = h_bf[d * 64 + lane];
    float ax = w * __uint_as_float(hv << 16);
    float ay = w * __uint_as_float(hv & 0xffff0000u);

    int lo = offsets[d], hi = offsets[d + 1];
    int k = lo;
    for (; k + 3 < hi; k += 4) {
        int s0 = src_sorted[k],     s1 = src_sorted[k + 1];
        int s2 = src_sorted[k + 2], s3 = src_sorted[k + 3];
        float e0 = a_s[s0 * NH + head] + ad;
        float e1 = a_s[s1 * NH + head] + ad;
        float e2 = a_s[s2 * NH + head] + ad;
        float e3 = a_s[s3 * NH + head] + ad;
        unsigned v0 = h_bf[s0 * 64 + lane];
        unsigned v1 = h_bf[s1 * 64 + lane];
        unsigned v2 = h_bf[s2 * 64 + lane];
        unsigned v3 = h_bf[s3 * 64 + lane];
        e0 = (e0 >= 0.f) ? e0 : NEG_SLOPE * e0;
        e1 = (e1 >= 0.f) ? e1 : NEG_SLOPE * e1;
        e2 = (e2 >= 0.f) ? e2 : NEG_SLOPE * e2;
        e3 = (e3 >= 0.f) ? e3 : NEG_SLOPE * e3;
        float w0 = __expf(e0), w1 = __expf(e1), w2 = __expf(e2), w3 = __expf(e3);
        denom += (w0 + w1) + (w2 + w3);
        ax += w0 * __uint_as_float(v0 << 16) + w1 * __uint_as_float(v1 << 16);
        ax += w2 * __uint_as_float(v2 << 16) + w3 * __uint_as_float(v3 << 16);
        ay += w0 * __uint_as_float(v0 & 0xffff0000u) + w1 * __uint_as_float(v1 & 0xffff0000u);
        ay += w2 * __uint_as_float(v2 & 0xffff0000u) + w3 * __uint_as_float(v3 & 0xffff0000u);
    }
    for (; k < hi; ++k) {
        int s0 = src_sorted[k];
        float e0 = a_s[s0 * NH + head] + ad;
        unsigned v0 = h_bf[s0 * 64 + lane];
        e0 = (e0 >= 0.f) ? e0 : NEG_SLOPE * e0;
        float w0 = __expf(e0);
        denom += w0;
        ax += w0 * __uint_as_float(v0 << 16);
        ay += w0 * __uint_as_float(v0 & 0xffff0000u);
    }

    float inv = 1.f / denom;
    float ox = ax * inv + bias[c0];
    float oy = ay * inv + bias[c0 + 1];
    ox = (ox > 0.f) ? ox : expm1f(ox);
    oy = (oy > 0.f) ? oy : expm1f(oy);
    float2 rv = *(const float2*)&r[d * HC + c0];
    ox += rv.x + res_b[c0];
    oy += rv.y + res_b[c0 + 1];
    float mean = wave_bcast_sum(ox + oy) * (1.f / HC);
    float dx = ox - mean, dy = oy - mean;
    float var = wave_bcast_sum(dx * dx + dy * dy) * (1.f / HC);
    float rs = rsqrtf(var + LN_EPS);
    *(float2*)&out[d * HC + c0] =
        make_float2(ln_g[c0] * dx * rs + ln_b[c0],
                    ln_g[c0 + 1] * dy * rs + ln_b[c0 + 1]);
}

// ---------------------------------------------------------------------------
extern "C" void kernel_launch(void* const* d_in, const int* in_sizes, int n_in,
                              void* d_out, int out_size, void* d_ws, size_t ws_size,
                              hipStream_t stream) {
    const float* x       = (const float*)d_in[0];
    const int*   ei      = (const int*)d_in[1];
    const float* W       = (const float*)d_in[2];
    const float* att_src = (const float*)d_in[3];
    const float* att_dst = (const float*)d_in[4];
    const float* bias    = (const float*)d_in[5];
    const float* res_w   = (const float*)d_in[6];
    const float* res_b   = (const float*)d_in[7];
    const float* ln_g    = (const float*)d_in[8];
    const float* ln_b    = (const float*)d_in[9];
    float* out = (float*)d_out;

    int n = in_sizes[0] / F_IN;          // 50000
    int E = in_sizes[1] / 2;             // 800000
    int nblk = (n + 255) / 256;          // 196 (<= 256)

    float*    r         = (float*)d_ws;                       // n*HC f32
    unsigned* h_bf      = (unsigned*)(r + (size_t)n * HC);    // n*64 dwords
    float*    a_s       = (float*)(h_bf + (size_t)n * 64);    // n*NH
    float*    a_d       = a_s + (size_t)n * NH;               // n*NH
    int*      offsets   = (int*)(a_d + (size_t)n * NH);       // n+1
    int*      bsums     = offsets + (n + 1);                  // 256
    int*      srcsorted = bsums + 256;                        // E
    int*      flag      = srcsorted + E;                      // 1

    hipMemsetAsync(offsets, 0, (size_t)(n + 1) * sizeof(int), stream);

    k0_detect<<<1, 256, 0, stream>>>(ei, E, flag);

    kA_gemm<<<(n + NT - 1) / NT, 256, 0, stream>>>(
        x, W, res_w, att_src, att_dst, h_bf, r, a_s, a_d, n);

    k_hist<<<(E + 255) / 256, 256, 0, stream>>>(ei, E, flag, offsets);

    k_scan_p1<<<nblk, 256, 0, stream>>>(offsets, n, bsums);
    k_scan_p2<<<1, 256, 0, stream>>>(bsums, nblk);
    k_scan_p3<<<nblk, 256, 0, stream>>>(offsets, bsums, n, E);

    int sc_blocks = (n + SC_RANGE - 1) / SC_RANGE;   // 98
    k_scatter2<<<sc_blocks, 1024, 0, stream>>>(ei, E, n, flag, offsets, srcsorted);

    k_agg<<<(n + 3) / 4, 256, 0, stream>>>(offsets, srcsorted, a_s, a_d, h_bf, r,
                                           bias, res_b, ln_g, ln_b, out, n);
}